// Round 6
// baseline (5840.139 us; speedup 1.0000x reference)
//
#include <hip/hip_runtime.h>

typedef __attribute__((ext_vector_type(4))) _Float16 half4_t;
typedef __attribute__((ext_vector_type(2))) float float2_t;

#define RD 256
#define NLAGS 512
#define NPAST 128
#define NT 1024

#if __has_builtin(__builtin_amdgcn_cvt_pk_f32_fp8) && __has_builtin(__builtin_amdgcn_cvt_pk_fp8_f32)
#define HAVE_FP8 1
#define SCLF (1.0f/4096.0f)
#else
#define HAVE_FP8 0
#define SCLF 1.0f
#endif

__device__ __forceinline__ float ftanh(float x) {
    float ax = __builtin_fabsf(x);
    float e = __builtin_amdgcn_exp2f(ax * 2.8853900817779268f);   // 2*log2(e)
    float r = 1.0f - 2.0f * __builtin_amdgcn_rcpf(e + 1.0f);
    return __builtin_copysignf(r, x);
}

__device__ __forceinline__ int swzi(int e) {      // float-index inside one R buffer
    int cc = e >> 2;
    int pc = cc ^ ((cc >> 3) & 7);
    return pc * 4 + (e & 3);
}

// VALU-only 16-lane ring reduction (DPP row_ror) — every lane gets the row16 sum
#define DPPADD(v, ctrl) { int _t = __builtin_amdgcn_update_dpp(0, __float_as_int(v), ctrl, 0xf, 0xf, true); \
                          (v) += __int_as_float(_t); }
#define RING16(v) DPPADD(v, 0x121) DPPADD(v, 0x122) DPPADD(v, 0x124) DPPADD(v, 0x128)

#define FOR_C(M) M(0) M(1) M(2) M(3)

#define DECL_RC(r, c) float4 b1_##r##_##c; half4_t hi_##r##_##c;
#define DECL_ALL \
    DECL_RC(0,0) DECL_RC(0,1) DECL_RC(0,2) DECL_RC(0,3) \
    DECL_RC(1,0) DECL_RC(1,1) DECL_RC(1,2) DECL_RC(1,3) \
    DECL_RC(2,0) DECL_RC(2,1) DECL_RC(2,2) DECL_RC(2,3) \
    DECL_RC(3,0) DECL_RC(3,1) DECL_RC(3,2) DECL_RC(3,3) \
    unsigned lw_0, lw_1, lw_2, lw_3;

#if HAVE_FP8
#define LO_PACK(r) { \
    unsigned wv = (unsigned)__builtin_amdgcn_cvt_pk_fp8_f32(l0, l1, 0, false); \
    wv = (unsigned)__builtin_amdgcn_cvt_pk_fp8_f32(l2, l3, (int)wv, true); \
    lw_##r = wv; }
#define LO_STORE(c) lo_lds[c][tid] = make_uint4(lw_0, lw_1, lw_2, lw_3);
#define LO_LOADC(c) uint4 Lq_##c = lo_lds[c][tid];
#define LO_FMA(r, c) { unsigned Lw = ((const unsigned*)&Lq_##c)[(r)]; \
    float2_t pA = __builtin_amdgcn_cvt_pk_f32_fp8((int)Lw, false); \
    float2_t pB = __builtin_amdgcn_cvt_pk_f32_fp8((int)Lw, true); \
    accl_##r = __builtin_fmaf(pA.x, rv.x, accl_##r); \
    accl_##r = __builtin_fmaf(pA.y, rv.y, accl_##r); \
    accl_##r = __builtin_fmaf(pB.x, rv.z, accl_##r); \
    accl_##r = __builtin_fmaf(pB.y, rv.w, accl_##r); }
#else
#define LO_PACK(r) { half4_t lv; \
    lv[0] = (_Float16)l0; lv[1] = (_Float16)l1; lv[2] = (_Float16)l2; lv[3] = (_Float16)l3; \
    lo_lds16[r][cc_][tid] = lv; }
#define LO_STORE(c)
#define LO_LOADC(c)
#define LO_FMA(r, c) { half4_t lv = lo_lds16[r][c][tid]; \
    accl_##r = __builtin_fmaf((float)lv[0], rv.x, accl_##r); \
    accl_##r = __builtin_fmaf((float)lv[1], rv.y, accl_##r); \
    accl_##r = __builtin_fmaf((float)lv[2], rv.z, accl_##r); \
    accl_##r = __builtin_fmaf((float)lv[3], rv.w, accl_##r); }
#endif

// stage one (row r, chunk c): B1*sc1 -> f32 regs; B2*sc2 -> f16 hi regs + lo residual
#define STG_RC(r, c) { \
    float4 a = *(const float4*)(Wm1 + (r)*RD + 4*(c)); \
    a.x *= sc1; a.y *= sc1; a.z *= sc1; a.w *= sc1; \
    b1_##r##_##c = a; \
    float4 e4 = *(const float4*)(Wm2 + (r)*RD + 4*(c)); \
    float q0 = sc2*e4.x, q1 = sc2*e4.y, q2 = sc2*e4.z, q3 = sc2*e4.w; \
    half4_t hv4; hv4[0]=(_Float16)q0; hv4[1]=(_Float16)q1; hv4[2]=(_Float16)q2; hv4[3]=(_Float16)q3; \
    hi_##r##_##c = hv4; \
    float l0 = (q0-(float)hv4[0])*(4096.0f*SCLF*4096.0f*SCLF==1.0f?4096.0f:4096.0f); \
    float l1 = (q1-(float)hv4[1])*4096.0f; \
    float l2 = (q2-(float)hv4[2])*4096.0f; \
    float l3 = (q3-(float)hv4[3])*4096.0f; \
    l0 = (q0-(float)hv4[0])*(HAVE_FP8?4096.0f:1.0f); \
    l1 = (q1-(float)hv4[1])*(HAVE_FP8?4096.0f:1.0f); \
    l2 = (q2-(float)hv4[2])*(HAVE_FP8?4096.0f:1.0f); \
    l3 = (q3-(float)hv4[3])*(HAVE_FP8?4096.0f:1.0f); \
    LO_PACK(r) }

#define STG_C(c) { const int cc_ = (c); (void)cc_; \
    STG_RC(0, c) STG_RC(1, c) STG_RC(2, c) STG_RC(3, c) LO_STORE(c) }

#define DOT_ROW(r, c) \
    acc1_##r = __builtin_fmaf(b1_##r##_##c.x, rv.x, acc1_##r); \
    acc1_##r = __builtin_fmaf(b1_##r##_##c.y, rv.y, acc1_##r); \
    acc1_##r = __builtin_fmaf(b1_##r##_##c.z, rv.z, acc1_##r); \
    acc1_##r = __builtin_fmaf(b1_##r##_##c.w, rv.w, acc1_##r); \
    acc2_##r = __builtin_fmaf((float)hi_##r##_##c[0], rv.x, acc2_##r); \
    acc2_##r = __builtin_fmaf((float)hi_##r##_##c[1], rv.y, acc2_##r); \
    acc2_##r = __builtin_fmaf((float)hi_##r##_##c[2], rv.z, acc2_##r); \
    acc2_##r = __builtin_fmaf((float)hi_##r##_##c[3], rv.w, acc2_##r); \
    LO_FMA(r, c)

#define DOT_C(c, roffv) { \
    float4 rv = *(const float4*)(RsB + (roffv)); \
    LO_LOADC(c) \
    DOT_ROW(0, c) DOT_ROW(1, c) DOT_ROW(2, c) DOT_ROW(3, c) }

// ---------------------------------------------------------------------------
// Main SDE scan: one block (1024 thr) per batch row.
// ---------------------------------------------------------------------------
__global__ __launch_bounds__(NT) void sde_main_kernel(
    const float* __restrict__ inc, const float* __restrict__ Vn,
    const float* __restrict__ W1h, const float* __restrict__ b1h,
    const float* __restrict__ W1o, const float* __restrict__ b1o,
    const float* __restrict__ rho1p, const float* __restrict__ rho2p,
    const float* __restrict__ rho3p, const float* __restrict__ rho4p,
    const float* __restrict__ B1, const float* __restrict__ B2,
    const float* __restrict__ lam1, const float* __restrict__ lam2,
    const float* __restrict__ Wr, const float* __restrict__ brp,
    const float* __restrict__ rsig, float* __restrict__ out)
{
    const int tid  = threadIdx.x;
    const int b    = blockIdx.x;
    const int ksub = tid & 15;          // K-slice 0..15 (16 cols each)
    const int g    = tid >> 4;          // row-group 0..63 (4 rows each)
    const int lane = tid & 63;
    const int wv   = tid >> 6;          // wave 0..15
    const int row0 = g << 2;
    const int myq  = ksub & 3;
    const int myrow = row0 + myq;

#if HAVE_FP8
    __shared__ __align__(16) uint4 lo_lds[4][NT];          // 64 KB fp8 residuals
#else
    __shared__ __align__(16) half4_t lo_lds16[4][4][NT];   // 128 KB f16 residuals
#endif
    __shared__ __align__(16) float Rs[2][RD];
    __shared__ __align__(16) float inc_lds[NLAGS];
    __shared__ float red[2][64];
    __shared__ float hv[32];

    const float rho1 = *rho1p, rho2 = *rho2p, rho3 = *rho3p, rho4 = *rho4p;

    DECL_ALL
    {
        const float sc1 = rho1, sc2 = rho3;
        const float* Wm1 = B1 + row0 * RD + (ksub << 4);
        const float* Wm2 = B2 + row0 * RD + (ksub << 4);
        FOR_C(STG_C)
    }
    const float c1m  = rho2 * lam1[myrow];
    const float c2m  = rho4 * lam2[myrow];
    const float wrim = Wr[myrow];
    const float brv  = *brp;

    // prologue staging
    if (tid < NLAGS) inc_lds[tid] = inc[b * NLAGS + tid];
    if (tid < 32) {
        float a = b1h[tid];
        const float* wrow = W1h + tid * 32;
        const float* vn = Vn + b * 32;
        for (int k = 0; k < 32; ++k) a = __builtin_fmaf(wrow[k], vn[k], a);
        hv[tid] = ftanh(a);
    }
    if (tid < RD - 30) ((float*)Rs)[swzi(tid)] = rsig[tid];
    __syncthreads();
    if (tid == 0) inc_lds[1] = inc_lds[0] + inc_lds[1];    // dW[0] = inc0+inc1
    if (tid < 30) {
        float a = b1o[tid];
        const float* wrow = W1o + tid * 32;
        for (int k = 0; k < 32; ++k) a = __builtin_fmaf(wrow[k], hv[k], a);
        ((float*)Rs)[swzi((RD - 30) + tid)] = a;
    }
    __syncthreads();

    float rmine = ((float*)Rs)[swzi(myrow)];

    // peeled readout of R0 -> out[b,0] (uses red[0])
    {
        float p0 = (ksub < 4) ? rmine * wrim : 0.0f;
        RING16(p0);
        if (ksub == 0) red[0][g] = p0;
    }
    __syncthreads();
    if (wv == 0) {
        float s = red[0][lane];
        RING16(s);
        s += __shfl_xor(s, 16, 64);
        s += __shfl_xor(s, 32, 64);
        if (lane == 0) out[(size_t)b * NLAGS] = s + brv;
    }

    char* RsB  = (char*)Rs;
    char* redB = (char*)red;
    int roff_0 = ((4 * ksub + 0) ^ (ksub >> 1)) << 4;
    int roff_1 = ((4 * ksub + 1) ^ (ksub >> 1)) << 4;
    int roff_2 = ((4 * ksub + 2) ^ (ksub >> 1)) << 4;
    int roff_3 = ((4 * ksub + 3) ^ (ksub >> 1)) << 4;
    int woff   = 1024 + swzi(myrow) * 4;     // writes go to buffer 1 first
    int redw   = 256 + (g << 2);             // red[1] first
    int redr   = 256 + (lane << 2);
    int incoff = 4;
    float* outp = out + (size_t)b * NLAGS;

#pragma unroll 1
    for (int t = 0; t < NLAGS - 1; ++t) {
        float dwt = *(const float*)((const char*)inc_lds + incoff);
        float acc1_0 = 0.f, acc1_1 = 0.f, acc1_2 = 0.f, acc1_3 = 0.f;
        float acc2_0 = 0.f, acc2_1 = 0.f, acc2_2 = 0.f, acc2_3 = 0.f;
        float accl_0 = 0.f, accl_1 = 0.f, accl_2 = 0.f, accl_3 = 0.f;
        DOT_C(0, roff_0) DOT_C(1, roff_1) DOT_C(2, roff_2) DOT_C(3, roff_3)
        float a2_0 = __builtin_fmaf(accl_0, SCLF, acc2_0);
        float a2_1 = __builtin_fmaf(accl_1, SCLF, acc2_1);
        float a2_2 = __builtin_fmaf(accl_2, SCLF, acc2_2);
        float a2_3 = __builtin_fmaf(accl_3, SCLF, acc2_3);
        RING16(acc1_0) RING16(acc1_1) RING16(acc1_2) RING16(acc1_3)
        RING16(a2_0)  RING16(a2_1)  RING16(a2_2)  RING16(a2_3)
        const bool qb0 = (ksub & 1) != 0, qb1 = (ksub & 2) != 0;
        float s1 = qb1 ? (qb0 ? acc1_3 : acc1_2) : (qb0 ? acc1_1 : acc1_0);
        float s2 = qb1 ? (qb0 ? a2_3  : a2_2)  : (qb0 ? a2_1  : a2_0);
        float drift = ftanh(s1 + c1m);
        float dif   = ftanh(s2 + c2m);
        rmine = rmine + drift + dif * dwt;
        if (ksub < 4) *(float*)(RsB + woff) = rmine;
        float p = (ksub < 4) ? rmine * wrim : 0.0f;
        RING16(p);
        if (ksub == 0) *(float*)(redB + redw) = p;
        __syncthreads();
        if (wv == 0) {
            float s = *(const float*)(redB + redr);
            RING16(s);
            s += __shfl_xor(s, 16, 64);
            s += __shfl_xor(s, 32, 64);
            if (lane == 0) outp[t + 1] = s + brv;
        }
        roff_0 ^= 1024; roff_1 ^= 1024; roff_2 ^= 1024; roff_3 ^= 1024;
        woff ^= 1024; redw ^= 256; redr ^= 256; incoff += 4;
    }
}

// ---------------------------------------------------------------------------
// rsig scan: one block (1024 thr); same structure, A-matrices, no readout.
// ---------------------------------------------------------------------------
__global__ __launch_bounds__(NT) void rsig_kernel(
    const float* __restrict__ xp,
    const float* __restrict__ A1, const float* __restrict__ A2,
    const float* __restrict__ xi1, const float* __restrict__ xi2,
    const float* __restrict__ W2h, const float* __restrict__ b2h,
    const float* __restrict__ W2o, const float* __restrict__ b2o,
    float* __restrict__ rsig_out)
{
    const int tid  = threadIdx.x;
    const int ksub = tid & 15;
    const int g    = tid >> 4;
    const int row0 = g << 2;
    const int myq  = ksub & 3;
    const int myrow = row0 + myq;

#if HAVE_FP8
    __shared__ __align__(16) uint4 lo_lds[4][NT];
#else
    __shared__ __align__(16) half4_t lo_lds16[4][4][NT];
#endif
    __shared__ __align__(16) float Rs[2][RD];
    __shared__ float dx_lds[NPAST];
    __shared__ float Zlin[RD];
    __shared__ float hh[32];

    DECL_ALL
    {
        const float sc1 = 1.0f, sc2 = 1.0f;
        const float* Wm1 = A1 + row0 * RD + (ksub << 4);
        const float* Wm2 = A2 + row0 * RD + (ksub << 4);
        FOR_C(STG_C)
    }
    const float x1m = xi1[myrow];
    const float x2m = xi2[myrow];

    if (tid < NPAST - 1) dx_lds[tid] = xp[tid + 1] - xp[tid];
    if (tid < 2 * RD) ((float*)Rs)[tid] = 0.0f;     // both buffers zero
    __syncthreads();

    float zmine = 0.0f;
    char* RsB = (char*)Rs;
    int roff_0 = ((4 * ksub + 0) ^ (ksub >> 1)) << 4;
    int roff_1 = ((4 * ksub + 1) ^ (ksub >> 1)) << 4;
    int roff_2 = ((4 * ksub + 2) ^ (ksub >> 1)) << 4;
    int roff_3 = ((4 * ksub + 3) ^ (ksub >> 1)) << 4;
    int woff   = 1024 + swzi(myrow) * 4;
    int dxoff  = 0;

#pragma unroll 1
    for (int t = 0; t < NPAST - 1; ++t) {
        float dxt = *(const float*)((const char*)dx_lds + dxoff);
        float acc1_0 = 0.f, acc1_1 = 0.f, acc1_2 = 0.f, acc1_3 = 0.f;
        float acc2_0 = 0.f, acc2_1 = 0.f, acc2_2 = 0.f, acc2_3 = 0.f;
        float accl_0 = 0.f, accl_1 = 0.f, accl_2 = 0.f, accl_3 = 0.f;
        DOT_C(0, roff_0) DOT_C(1, roff_1) DOT_C(2, roff_2) DOT_C(3, roff_3)
        float a2_0 = __builtin_fmaf(accl_0, SCLF, acc2_0);
        float a2_1 = __builtin_fmaf(accl_1, SCLF, acc2_1);
        float a2_2 = __builtin_fmaf(accl_2, SCLF, acc2_2);
        float a2_3 = __builtin_fmaf(accl_3, SCLF, acc2_3);
        RING16(acc1_0) RING16(acc1_1) RING16(acc1_2) RING16(acc1_3)
        RING16(a2_0)  RING16(a2_1)  RING16(a2_2)  RING16(a2_3)
        const bool qb0 = (ksub & 1) != 0, qb1 = (ksub & 2) != 0;
        float s1 = qb1 ? (qb0 ? acc1_3 : acc1_2) : (qb0 ? acc1_1 : acc1_0);
        float s2 = qb1 ? (qb0 ? a2_3  : a2_2)  : (qb0 ? a2_1  : a2_0);
        zmine = zmine + ftanh(s1 + x1m) + ftanh(s2 + x2m) * dxt;
        if (ksub < 4) *(float*)(RsB + woff) = zmine;
        __syncthreads();
        roff_0 ^= 1024; roff_1 ^= 1024; roff_2 ^= 1024; roff_3 ^= 1024;
        woff ^= 1024; dxoff += 4;
    }

    if (ksub < 4) Zlin[myrow] = zmine;
    __syncthreads();

    if (tid < 32) {
        float a = b2h[tid];
        const float* wrow = W2h + tid * RD;
        for (int k = 0; k < RD; ++k) a = __builtin_fmaf(wrow[k], Zlin[k], a);
        hh[tid] = ftanh(a);
    }
    __syncthreads();
    if (tid < RD - 30) {
        float a = b2o[tid];
        const float* wrow = W2o + tid * 32;
        for (int k = 0; k < 32; ++k) a = __builtin_fmaf(wrow[k], hh[k], a);
        rsig_out[tid] = a;
    }
}

extern "C" void kernel_launch(void* const* d_in, const int* in_sizes, int n_in,
                              void* d_out, int out_size, void* d_ws, size_t ws_size,
                              hipStream_t stream) {
    const float* x_past  = (const float*)d_in[2];
    const float* V_noise = (const float*)d_in[3];
    const float* inc     = (const float*)d_in[4];
    const float* W1h     = (const float*)d_in[5];
    const float* b1h     = (const float*)d_in[6];
    const float* W1o     = (const float*)d_in[7];
    const float* b1o     = (const float*)d_in[8];
    const float* W2h     = (const float*)d_in[9];
    const float* b2h     = (const float*)d_in[10];
    const float* W2o     = (const float*)d_in[11];
    const float* b2o     = (const float*)d_in[12];
    const float* rho1    = (const float*)d_in[13];
    const float* rho2    = (const float*)d_in[14];
    const float* rho3    = (const float*)d_in[15];
    const float* rho4    = (const float*)d_in[16];
    const float* B1      = (const float*)d_in[17];
    const float* B2      = (const float*)d_in[18];
    const float* lam1    = (const float*)d_in[19];
    const float* lam2    = (const float*)d_in[20];
    const float* A1      = (const float*)d_in[21];
    const float* A2      = (const float*)d_in[22];
    const float* xi1     = (const float*)d_in[23];
    const float* xi2     = (const float*)d_in[24];
    const float* Wr      = (const float*)d_in[25];
    const float* br      = (const float*)d_in[26];

    float* rsig_ws = (float*)d_ws;   // 226 floats

    rsig_kernel<<<1, NT, 0, stream>>>(x_past, A1, A2, xi1, xi2,
                                      W2h, b2h, W2o, b2o, rsig_ws);

    sde_main_kernel<<<256, NT, 0, stream>>>(inc, V_noise, W1h, b1h, W1o, b1o,
                                            rho1, rho2, rho3, rho4,
                                            B1, B2, lam1, lam2, Wr, br,
                                            rsig_ws, (float*)d_out);
}

// Round 7
// 4819.357 us; speedup vs baseline: 1.2118x; 1.2118x over previous
//
#include <hip/hip_runtime.h>

typedef __attribute__((ext_vector_type(4))) float f32x4;
typedef __attribute__((ext_vector_type(2))) float f32x2;
typedef __attribute__((ext_vector_type(8))) _Float16 h16x8;

#define RD 256
#define NLAGS 512
#define NPAST 128

__device__ __forceinline__ float ftanh(float x) {
    float ax = __builtin_fabsf(x);
    float e = __builtin_amdgcn_exp2f(ax * 2.8853900817779268f);   // 2*log2(e)
    float r = 1.0f - 2.0f * __builtin_amdgcn_rcpf(e + 1.0f);
    return __builtin_copysignf(r, x);
}

// DPP quad-perm butterfly add (pure VALU, no DS): xor1 = [1,0,3,2]=0xB1, xor2 = [2,3,0,1]=0x4E
#define DPPADD(v, ctrl) { int _t = __builtin_amdgcn_update_dpp(0, __float_as_int(v), ctrl, 0xf, 0xf, true); \
                          (v) += __int_as_float(_t); }
#define QUADSUM(v) DPPADD(v, 0xB1) DPPADD(v, 0x4E)

#define RPT16(M) M(0) M(1) M(2) M(3) M(4) M(5) M(6) M(7) M(8) M(9) M(10) M(11) M(12) M(13) M(14) M(15)
#define RPTP(M) M(0,0,1) M(1,2,3) M(2,4,5) M(3,6,7) M(4,8,9) M(5,10,11) M(6,12,13) M(7,14,15)

// per-thread weight registers: 2 rows x 64 cols; B1 f32 (32 f32x4 = 128 VGPR),
// B2 hi f16 (16 h16x8 = 64 VGPR), B2 lo residual fp8 x4096 in LDS (128 B/thread)
#define DECL_W(c) f32x4 b1r0_##c, b1r1_##c; h16x8 hi2_##c; unsigned lwA_##c, lwB_##c;

#define STG(c) { \
    int off = (((c) << 4) + q64) & 0xF0; \
    f32x4 a0 = *(const f32x4*)(pB1 + off); \
    f32x4 a1 = *(const f32x4*)(pB1 + 1024 + off); \
    b1r0_##c = a0 * sc1; b1r1_##c = a1 * sc1; \
    f32x4 e0 = *(const f32x4*)(pB2 + off) * sc2; \
    f32x4 e1 = *(const f32x4*)(pB2 + 1024 + off) * sc2; \
    h16x8 hv; \
    hv[0]=(_Float16)e0[0]; hv[1]=(_Float16)e0[1]; hv[2]=(_Float16)e0[2]; hv[3]=(_Float16)e0[3]; \
    hv[4]=(_Float16)e1[0]; hv[5]=(_Float16)e1[1]; hv[6]=(_Float16)e1[2]; hv[7]=(_Float16)e1[3]; \
    hi2_##c = hv; \
    float l0=(e0[0]-(float)hv[0])*4096.f, l1=(e0[1]-(float)hv[1])*4096.f; \
    float l2=(e0[2]-(float)hv[2])*4096.f, l3=(e0[3]-(float)hv[3])*4096.f; \
    float m0=(e1[0]-(float)hv[4])*4096.f, m1=(e1[1]-(float)hv[5])*4096.f; \
    float m2=(e1[2]-(float)hv[6])*4096.f, m3=(e1[3]-(float)hv[7])*4096.f; \
    unsigned uA = (unsigned)__builtin_amdgcn_cvt_pk_fp8_f32(l0, l1, 0, false); \
    uA = (unsigned)__builtin_amdgcn_cvt_pk_fp8_f32(l2, l3, (int)uA, true); \
    unsigned uB = (unsigned)__builtin_amdgcn_cvt_pk_fp8_f32(m0, m1, 0, false); \
    uB = (unsigned)__builtin_amdgcn_cvt_pk_fp8_f32(m2, m3, (int)uB, true); \
    lwA_##c = uA; lwB_##c = uB; }

// opaque pin: forbids remat-from-global and spill-avoidance tricks
#define KEEPW(c) asm volatile("" : "+v"(b1r0_##c), "+v"(b1r1_##c), "+v"(hi2_##c));

#define STO(p, c0, c1) lo_lds[((p) << 9) + tid] = make_uint4(lwA_##c0, lwB_##c0, lwA_##c1, lwB_##c1);

#define F4(acc, wv, rv) \
    acc = __builtin_fmaf(wv[0], rv[0], acc); \
    acc = __builtin_fmaf(wv[1], rv[1], acc); \
    acc = __builtin_fmaf(wv[2], rv[2], acc); \
    acc = __builtin_fmaf(wv[3], rv[3], acc);

#define F4H(acc, hv, b, rv) \
    acc = __builtin_fmaf((float)hv[(b)+0], rv[0], acc); \
    acc = __builtin_fmaf((float)hv[(b)+1], rv[1], acc); \
    acc = __builtin_fmaf((float)hv[(b)+2], rv[2], acc); \
    acc = __builtin_fmaf((float)hv[(b)+3], rv[3], acc);

#define F4L(acc, w, rv) { \
    f32x2 pA_ = __builtin_amdgcn_cvt_pk_f32_fp8((int)(w), false); \
    f32x2 pB_ = __builtin_amdgcn_cvt_pk_f32_fp8((int)(w), true); \
    acc = __builtin_fmaf(pA_[0], rv[0], acc); \
    acc = __builtin_fmaf(pA_[1], rv[1], acc); \
    acc = __builtin_fmaf(pB_[0], rv[2], acc); \
    acc = __builtin_fmaf(pB_[1], rv[3], acc); }

#define DOT1(c, wA, wB) { \
    f32x4 rv = *(const f32x4*)(RqR + ((((c) << 4) + q64) & 0xF0)); \
    F4(acc1_0, b1r0_##c, rv) F4(acc1_1, b1r1_##c, rv) \
    F4H(acc2_0, hi2_##c, 0, rv) F4H(acc2_1, hi2_##c, 4, rv) \
    F4L(accl_0, wA, rv) F4L(accl_1, wB, rv) }

#define DOTP(p, c0, c1) { \
    uint4 Lq = lo_lds[((p) << 9) + tid]; \
    const unsigned* Lw = (const unsigned*)&Lq; \
    DOT1(c0, Lw[0], Lw[1]) \
    DOT1(c1, Lw[2], Lw[3]) }

#define SCLF (1.0f / 4096.0f)

// ---------------------------------------------------------------------------
// Main SDE scan: one block (512 thr) per batch row.
// thread = (row-pair g = tid>>2, K-slice q = tid&3 of 64 cols)
// ---------------------------------------------------------------------------
__global__ void __launch_bounds__(512, 2) sde_main_kernel(
    const float* __restrict__ inc, const float* __restrict__ Vn,
    const float* __restrict__ W1h, const float* __restrict__ b1h,
    const float* __restrict__ W1o, const float* __restrict__ b1o,
    const float* __restrict__ rho1p, const float* __restrict__ rho2p,
    const float* __restrict__ rho3p, const float* __restrict__ rho4p,
    const float* __restrict__ B1, const float* __restrict__ B2,
    const float* __restrict__ lam1, const float* __restrict__ lam2,
    const float* __restrict__ Wr, const float* __restrict__ brp,
    const float* __restrict__ rsig, float* __restrict__ out)
{
    const int tid  = threadIdx.x;
    const int b    = blockIdx.x;
    const int q    = tid & 3;           // K-slice (64 cols)
    const int g    = tid >> 2;          // row-pair 0..127
    const int lane = tid & 63;
    const int wvi  = tid >> 6;
    const int q64  = q << 6;
    const int myrow = 2 * g + (q & 1);

    __shared__ __align__(16) uint4 lo_lds[8 * 512];       // 64 KB fp8 residuals
    __shared__ __align__(16) float Rs[2][RD];
    __shared__ __align__(16) float inc_lds[NLAGS];
    __shared__ float red[2][8];
    __shared__ float hv[32];

    const float rho1 = *rho1p, rho2 = *rho2p, rho3 = *rho3p, rho4 = *rho4p;

    RPT16(DECL_W)
    {
        const float sc1 = rho1, sc2 = rho3;
        const char* pB1 = (const char*)(B1 + (2 * g) * RD) + (q << 8);
        const char* pB2 = (const char*)(B2 + (2 * g) * RD) + (q << 8);
        RPT16(STG)
        RPTP(STO)
    }
    RPT16(KEEPW)

    const float c1m  = rho2 * lam1[myrow];
    const float c2m  = rho4 * lam2[myrow];
    const float wrim = Wr[myrow];
    const float brv  = *brp;

    // prologue: increments, initial condition R0 = [rsig ; V]
    inc_lds[tid] = inc[b * NLAGS + tid];
    if (tid < 32) {
        float a = b1h[tid];
        const float* wrow = W1h + tid * 32;
        const float* vn = Vn + b * 32;
        for (int k = 0; k < 32; ++k) a = __builtin_fmaf(wrow[k], vn[k], a);
        hv[tid] = ftanh(a);
    }
    if (tid < RD - 30) ((float*)Rs)[tid] = rsig[tid];
    __syncthreads();
    if (tid == 0) inc_lds[1] = inc_lds[0] + inc_lds[1];   // dW[0] = inc0 + inc1
    if (tid < 30) {
        float a = b1o[tid];
        const float* wrow = W1o + tid * 32;
        for (int k = 0; k < 32; ++k) a = __builtin_fmaf(wrow[k], hv[k], a);
        ((float*)Rs)[(RD - 30) + tid] = a;
    }
    __syncthreads();

    float rmine = ((const float*)Rs)[myrow];

    // peeled readout of R0 -> out[b,0]
    {
        float p = (q < 2) ? rmine * wrim : 0.0f;
        QUADSUM(p)
        p += __shfl_xor(p, 4, 64);
        p += __shfl_xor(p, 8, 64);
        p += __shfl_xor(p, 16, 64);
        p += __shfl_xor(p, 32, 64);
        if (lane == 0) red[0][wvi] = p;
    }
    __syncthreads();
    if (wvi == 0) {
        float s = (lane < 8) ? red[0][lane] : 0.0f;
        s += __shfl_xor(s, 1, 64);
        s += __shfl_xor(s, 2, 64);
        s += __shfl_xor(s, 4, 64);
        if (lane == 0) out[(size_t)b * NLAGS] = s + brv;
    }

    char* RsB = (char*)Rs;
    int rbase = 0;
    float* outp = out + (size_t)b * NLAGS;

#pragma unroll 1
    for (int t = 0; t < NLAGS - 1; ++t) {
        const float dwt = inc_lds[t + 1];
        const char* RqR = RsB + rbase + (q << 8);
        float acc1_0 = 0.f, acc1_1 = 0.f, acc2_0 = 0.f, acc2_1 = 0.f;
        float accl_0 = 0.f, accl_1 = 0.f;
        RPTP(DOTP)
        float a1_0 = acc1_0, a1_1 = acc1_1;
        float a2_0 = __builtin_fmaf(accl_0, SCLF, acc2_0);
        float a2_1 = __builtin_fmaf(accl_1, SCLF, acc2_1);
        QUADSUM(a1_0) QUADSUM(a1_1) QUADSUM(a2_0) QUADSUM(a2_1)
        float s1 = (q & 1) ? a1_1 : a1_0;
        float s2 = (q & 1) ? a2_1 : a2_0;
        float rn = rmine + ftanh(s1 + c1m) + ftanh(s2 + c2m) * dwt;
        rmine = rn;
        if (q < 2) *(float*)(RsB + (rbase ^ 1024) + myrow * 4) = rn;
        float p = (q < 2) ? rn * wrim : 0.0f;
        QUADSUM(p)
        p += __shfl_xor(p, 4, 64);
        p += __shfl_xor(p, 8, 64);
        p += __shfl_xor(p, 16, 64);
        p += __shfl_xor(p, 32, 64);
        const int slot = (t + 1) & 1;
        if (lane == 0) red[slot][wvi] = p;
        __syncthreads();
        if (wvi == 0) {
            float s = (lane < 8) ? red[slot][lane] : 0.0f;
            s += __shfl_xor(s, 1, 64);
            s += __shfl_xor(s, 2, 64);
            s += __shfl_xor(s, 4, 64);
            if (lane == 0) outp[t + 1] = s + brv;
        }
        rbase ^= 1024;
    }
}

// ---------------------------------------------------------------------------
// rsig scan (batch-independent), one block; same structure on A1/A2.
// ---------------------------------------------------------------------------
__global__ void __launch_bounds__(512, 2) rsig_kernel(
    const float* __restrict__ xp,
    const float* __restrict__ A1, const float* __restrict__ A2,
    const float* __restrict__ xi1, const float* __restrict__ xi2,
    const float* __restrict__ W2h, const float* __restrict__ b2h,
    const float* __restrict__ W2o, const float* __restrict__ b2o,
    float* __restrict__ rsig_out)
{
    const int tid = threadIdx.x;
    const int q   = tid & 3;
    const int g   = tid >> 2;
    const int q64 = q << 6;
    const int myrow = 2 * g + (q & 1);

    __shared__ __align__(16) uint4 lo_lds[8 * 512];       // 64 KB
    __shared__ __align__(16) float Rs[2][RD];
    __shared__ float dx_lds[NPAST];
    __shared__ float Zlin[RD];
    __shared__ float hh[32];

    RPT16(DECL_W)
    {
        const float sc1 = 1.0f, sc2 = 1.0f;
        const char* pB1 = (const char*)(A1 + (2 * g) * RD) + (q << 8);
        const char* pB2 = (const char*)(A2 + (2 * g) * RD) + (q << 8);
        RPT16(STG)
        RPTP(STO)
    }
    RPT16(KEEPW)

    const float x1m = xi1[myrow];
    const float x2m = xi2[myrow];

    if (tid < NPAST - 1) dx_lds[tid] = xp[tid + 1] - xp[tid];
    ((float*)Rs)[tid] = 0.0f;           // zero both buffers (512 floats)
    __syncthreads();

    float zmine = 0.0f;
    char* RsB = (char*)Rs;
    int rbase = 0;

#pragma unroll 1
    for (int t = 0; t < NPAST - 1; ++t) {
        const float dxt = dx_lds[t];
        const char* RqR = RsB + rbase + (q << 8);
        float acc1_0 = 0.f, acc1_1 = 0.f, acc2_0 = 0.f, acc2_1 = 0.f;
        float accl_0 = 0.f, accl_1 = 0.f;
        RPTP(DOTP)
        float a1_0 = acc1_0, a1_1 = acc1_1;
        float a2_0 = __builtin_fmaf(accl_0, SCLF, acc2_0);
        float a2_1 = __builtin_fmaf(accl_1, SCLF, acc2_1);
        QUADSUM(a1_0) QUADSUM(a1_1) QUADSUM(a2_0) QUADSUM(a2_1)
        float s1 = (q & 1) ? a1_1 : a1_0;
        float s2 = (q & 1) ? a2_1 : a2_0;
        zmine = zmine + ftanh(s1 + x1m) + ftanh(s2 + x2m) * dxt;
        if (q < 2) *(float*)(RsB + (rbase ^ 1024) + myrow * 4) = zmine;
        __syncthreads();
        rbase ^= 1024;
    }

    if (q < 2) Zlin[myrow] = zmine;
    __syncthreads();

    if (tid < 32) {
        float a = b2h[tid];
        const float* wrow = W2h + tid * RD;
        for (int k = 0; k < RD; ++k) a = __builtin_fmaf(wrow[k], Zlin[k], a);
        hh[tid] = ftanh(a);
    }
    __syncthreads();
    if (tid < RD - 30) {
        float a = b2o[tid];
        const float* wrow = W2o + tid * 32;
        for (int k = 0; k < 32; ++k) a = __builtin_fmaf(wrow[k], hh[k], a);
        rsig_out[tid] = a;
    }
}

extern "C" void kernel_launch(void* const* d_in, const int* in_sizes, int n_in,
                              void* d_out, int out_size, void* d_ws, size_t ws_size,
                              hipStream_t stream) {
    const float* x_past  = (const float*)d_in[2];
    const float* V_noise = (const float*)d_in[3];
    const float* inc     = (const float*)d_in[4];
    const float* W1h     = (const float*)d_in[5];
    const float* b1h     = (const float*)d_in[6];
    const float* W1o     = (const float*)d_in[7];
    const float* b1o     = (const float*)d_in[8];
    const float* W2h     = (const float*)d_in[9];
    const float* b2h     = (const float*)d_in[10];
    const float* W2o     = (const float*)d_in[11];
    const float* b2o     = (const float*)d_in[12];
    const float* rho1    = (const float*)d_in[13];
    const float* rho2    = (const float*)d_in[14];
    const float* rho3    = (const float*)d_in[15];
    const float* rho4    = (const float*)d_in[16];
    const float* B1      = (const float*)d_in[17];
    const float* B2      = (const float*)d_in[18];
    const float* lam1    = (const float*)d_in[19];
    const float* lam2    = (const float*)d_in[20];
    const float* A1      = (const float*)d_in[21];
    const float* A2      = (const float*)d_in[22];
    const float* xi1     = (const float*)d_in[23];
    const float* xi2     = (const float*)d_in[24];
    const float* Wr      = (const float*)d_in[25];
    const float* br      = (const float*)d_in[26];

    float* rsig_ws = (float*)d_ws;   // 226 floats

    rsig_kernel<<<1, 512, 0, stream>>>(x_past, A1, A2, xi1, xi2,
                                       W2h, b2h, W2o, b2o, rsig_ws);

    sde_main_kernel<<<256, 512, 0, stream>>>(inc, V_noise, W1h, b1h, W1o, b1o,
                                             rho1, rho2, rho3, rho4,
                                             B1, B2, lam1, lam2, Wr, br,
                                             rsig_ws, (float*)d_out);
}

// Round 8
// 4806.665 us; speedup vs baseline: 1.2150x; 1.0026x over previous
//
#include <hip/hip_runtime.h>

typedef __attribute__((ext_vector_type(4))) float f32x4;
typedef __attribute__((ext_vector_type(2))) float f32x2;
typedef __attribute__((ext_vector_type(8))) _Float16 h16x8;

#define RD 256
#define NLAGS 512
#define NPAST 128

__device__ __forceinline__ float ftanh(float x) {
    float ax = __builtin_fabsf(x);
    float e = __builtin_amdgcn_exp2f(ax * 2.8853900817779268f);   // 2*log2(e)
    float r = 1.0f - 2.0f * __builtin_amdgcn_rcpf(e + 1.0f);
    return __builtin_copysignf(r, x);
}

// DPP quad-perm butterfly add (pure VALU, no DS): xor1 = [1,0,3,2]=0xB1, xor2 = [2,3,0,1]=0x4E
#define DPPADD(v, ctrl) { int _t = __builtin_amdgcn_update_dpp(0, __float_as_int(v), ctrl, 0xf, 0xf, true); \
                          (v) += __int_as_float(_t); }
#define QUADSUM(v) DPPADD(v, 0xB1) DPPADD(v, 0x4E)

#define RPT16(M) M(0) M(1) M(2) M(3) M(4) M(5) M(6) M(7) M(8) M(9) M(10) M(11) M(12) M(13) M(14) M(15)
#define RPTP(M) M(0,0,1) M(1,2,3) M(2,4,5) M(3,6,7) M(4,8,9) M(5,10,11) M(6,12,13) M(7,14,15)

// per-thread weight registers: 2 rows x 64 cols; B1 f32 (32 f32x4 = 128 VGPR),
// B2 hi f16 (16 h16x8 = 64 VGPR), B2 lo residual fp8 x4096 in LDS (128 B/thread)
#define DECL_W(c) f32x4 b1r0_##c, b1r1_##c; h16x8 hi2_##c; unsigned lwA_##c, lwB_##c;

#define STG(c) { \
    int off = (((c) << 4) + q64) & 0xF0; \
    f32x4 a0 = *(const f32x4*)(pB1 + off); \
    f32x4 a1 = *(const f32x4*)(pB1 + 1024 + off); \
    b1r0_##c = a0 * sc1; b1r1_##c = a1 * sc1; \
    f32x4 e0 = *(const f32x4*)(pB2 + off) * sc2; \
    f32x4 e1 = *(const f32x4*)(pB2 + 1024 + off) * sc2; \
    h16x8 hv; \
    hv[0]=(_Float16)e0[0]; hv[1]=(_Float16)e0[1]; hv[2]=(_Float16)e0[2]; hv[3]=(_Float16)e0[3]; \
    hv[4]=(_Float16)e1[0]; hv[5]=(_Float16)e1[1]; hv[6]=(_Float16)e1[2]; hv[7]=(_Float16)e1[3]; \
    hi2_##c = hv; \
    float l0=(e0[0]-(float)hv[0])*4096.f, l1=(e0[1]-(float)hv[1])*4096.f; \
    float l2=(e0[2]-(float)hv[2])*4096.f, l3=(e0[3]-(float)hv[3])*4096.f; \
    float m0=(e1[0]-(float)hv[4])*4096.f, m1=(e1[1]-(float)hv[5])*4096.f; \
    float m2=(e1[2]-(float)hv[6])*4096.f, m3=(e1[3]-(float)hv[7])*4096.f; \
    unsigned uA = (unsigned)__builtin_amdgcn_cvt_pk_fp8_f32(l0, l1, 0, false); \
    uA = (unsigned)__builtin_amdgcn_cvt_pk_fp8_f32(l2, l3, (int)uA, true); \
    unsigned uB = (unsigned)__builtin_amdgcn_cvt_pk_fp8_f32(m0, m1, 0, false); \
    uB = (unsigned)__builtin_amdgcn_cvt_pk_fp8_f32(m2, m3, (int)uB, true); \
    lwA_##c = uA; lwB_##c = uB; }

// opaque pin: forbids remat-from-global and spill-avoidance tricks
#define KEEPW(c) asm volatile("" : "+v"(b1r0_##c), "+v"(b1r1_##c), "+v"(hi2_##c));

#define STO(p, c0, c1) lo_lds[((p) << 9) + tid] = make_uint4(lwA_##c0, lwB_##c0, lwA_##c1, lwB_##c1);

#define F4(acc, wv, rv) \
    acc = __builtin_fmaf(wv[0], rv[0], acc); \
    acc = __builtin_fmaf(wv[1], rv[1], acc); \
    acc = __builtin_fmaf(wv[2], rv[2], acc); \
    acc = __builtin_fmaf(wv[3], rv[3], acc);

#define F4H(acc, hv, b, rv) \
    acc = __builtin_fmaf((float)hv[(b)+0], rv[0], acc); \
    acc = __builtin_fmaf((float)hv[(b)+1], rv[1], acc); \
    acc = __builtin_fmaf((float)hv[(b)+2], rv[2], acc); \
    acc = __builtin_fmaf((float)hv[(b)+3], rv[3], acc);

#define F4L(acc, w, rv) { \
    f32x2 pA_ = __builtin_amdgcn_cvt_pk_f32_fp8((int)(w), false); \
    f32x2 pB_ = __builtin_amdgcn_cvt_pk_f32_fp8((int)(w), true); \
    acc = __builtin_fmaf(pA_[0], rv[0], acc); \
    acc = __builtin_fmaf(pA_[1], rv[1], acc); \
    acc = __builtin_fmaf(pB_[0], rv[2], acc); \
    acc = __builtin_fmaf(pB_[1], rv[3], acc); }

#define DOT1(c, wA, wB) { \
    f32x4 rv = *(const f32x4*)(RqR + ((((c) << 4) + q64) & 0xF0)); \
    F4(acc1_0, b1r0_##c, rv) F4(acc1_1, b1r1_##c, rv) \
    F4H(acc2_0, hi2_##c, 0, rv) F4H(acc2_1, hi2_##c, 4, rv) \
    F4L(accl_0, wA, rv) F4L(accl_1, wB, rv) }

#define DOTP(p, c0, c1) { \
    uint4 Lq = lo_lds[((p) << 9) + tid]; \
    const unsigned* Lw = (const unsigned*)&Lq; \
    DOT1(c0, Lw[0], Lw[1]) \
    DOT1(c1, Lw[2], Lw[3]) }

#define SCLF (1.0f / 4096.0f)

// ---------------------------------------------------------------------------
// Main SDE scan: one block (512 thr) per batch row.
// thread = (row-pair g = tid>>2, K-slice q = tid&3 of 64 cols)
// ---------------------------------------------------------------------------
__global__ void __launch_bounds__(512, 1) sde_main_kernel(
    const float* __restrict__ inc, const float* __restrict__ Vn,
    const float* __restrict__ W1h, const float* __restrict__ b1h,
    const float* __restrict__ W1o, const float* __restrict__ b1o,
    const float* __restrict__ rho1p, const float* __restrict__ rho2p,
    const float* __restrict__ rho3p, const float* __restrict__ rho4p,
    const float* __restrict__ B1, const float* __restrict__ B2,
    const float* __restrict__ lam1, const float* __restrict__ lam2,
    const float* __restrict__ Wr, const float* __restrict__ brp,
    const float* __restrict__ rsig, float* __restrict__ out)
{
    const int tid  = threadIdx.x;
    const int b    = blockIdx.x;
    const int q    = tid & 3;           // K-slice (64 cols)
    const int g    = tid >> 2;          // row-pair 0..127
    const int lane = tid & 63;
    const int wvi  = tid >> 6;
    const int q64  = q << 6;
    const int myrow = 2 * g + (q & 1);

    __shared__ __align__(16) uint4 lo_lds[8 * 512];       // 64 KB fp8 residuals
    __shared__ __align__(16) float Rs[2][RD];
    __shared__ __align__(16) float inc_lds[NLAGS];
    __shared__ float red[2][8];
    __shared__ float hv[32];

    const float rho1 = *rho1p, rho2 = *rho2p, rho3 = *rho3p, rho4 = *rho4p;

    RPT16(DECL_W)
    {
        const float sc1 = rho1, sc2 = rho3;
        const char* pB1 = (const char*)(B1 + (2 * g) * RD) + (q << 8);
        const char* pB2 = (const char*)(B2 + (2 * g) * RD) + (q << 8);
        RPT16(STG)
        RPTP(STO)
    }
    RPT16(KEEPW)

    const float c1m  = rho2 * lam1[myrow];
    const float c2m  = rho4 * lam2[myrow];
    const float wrim = Wr[myrow];
    const float brv  = *brp;

    // prologue: increments, initial condition R0 = [rsig ; V]
    inc_lds[tid] = inc[b * NLAGS + tid];
    if (tid < 32) {
        float a = b1h[tid];
        const float* wrow = W1h + tid * 32;
        const float* vn = Vn + b * 32;
        for (int k = 0; k < 32; ++k) a = __builtin_fmaf(wrow[k], vn[k], a);
        hv[tid] = ftanh(a);
    }
    if (tid < RD - 30) ((float*)Rs)[tid] = rsig[tid];
    __syncthreads();
    if (tid == 0) inc_lds[1] = inc_lds[0] + inc_lds[1];   // dW[0] = inc0 + inc1
    if (tid < 30) {
        float a = b1o[tid];
        const float* wrow = W1o + tid * 32;
        for (int k = 0; k < 32; ++k) a = __builtin_fmaf(wrow[k], hv[k], a);
        ((float*)Rs)[(RD - 30) + tid] = a;
    }
    __syncthreads();

    float rmine = ((const float*)Rs)[myrow];

    // peeled readout of R0 -> out[b,0]
    {
        float p = (q < 2) ? rmine * wrim : 0.0f;
        QUADSUM(p)
        p += __shfl_xor(p, 4, 64);
        p += __shfl_xor(p, 8, 64);
        p += __shfl_xor(p, 16, 64);
        p += __shfl_xor(p, 32, 64);
        if (lane == 0) red[0][wvi] = p;
    }
    __syncthreads();
    if (wvi == 0) {
        float s = (lane < 8) ? red[0][lane] : 0.0f;
        s += __shfl_xor(s, 1, 64);
        s += __shfl_xor(s, 2, 64);
        s += __shfl_xor(s, 4, 64);
        if (lane == 0) out[(size_t)b * NLAGS] = s + brv;
    }

    char* RsB = (char*)Rs;
    int rbase = 0;
    float* outp = out + (size_t)b * NLAGS;

#pragma unroll 1
    for (int t = 0; t < NLAGS - 1; ++t) {
        const float dwt = inc_lds[t + 1];
        const char* RqR = RsB + rbase + (q << 8);
        float acc1_0 = 0.f, acc1_1 = 0.f, acc2_0 = 0.f, acc2_1 = 0.f;
        float accl_0 = 0.f, accl_1 = 0.f;
        RPTP(DOTP)
        float a1_0 = acc1_0, a1_1 = acc1_1;
        float a2_0 = __builtin_fmaf(accl_0, SCLF, acc2_0);
        float a2_1 = __builtin_fmaf(accl_1, SCLF, acc2_1);
        QUADSUM(a1_0) QUADSUM(a1_1) QUADSUM(a2_0) QUADSUM(a2_1)
        float s1 = (q & 1) ? a1_1 : a1_0;
        float s2 = (q & 1) ? a2_1 : a2_0;
        float rn = rmine + ftanh(s1 + c1m) + ftanh(s2 + c2m) * dwt;
        rmine = rn;
        if (q < 2) *(float*)(RsB + (rbase ^ 1024) + myrow * 4) = rn;
        float p = (q < 2) ? rn * wrim : 0.0f;
        QUADSUM(p)
        p += __shfl_xor(p, 4, 64);
        p += __shfl_xor(p, 8, 64);
        p += __shfl_xor(p, 16, 64);
        p += __shfl_xor(p, 32, 64);
        const int slot = (t + 1) & 1;
        if (lane == 0) red[slot][wvi] = p;
        __syncthreads();
        if (wvi == 0) {
            float s = (lane < 8) ? red[slot][lane] : 0.0f;
            s += __shfl_xor(s, 1, 64);
            s += __shfl_xor(s, 2, 64);
            s += __shfl_xor(s, 4, 64);
            if (lane == 0) outp[t + 1] = s + brv;
        }
        rbase ^= 1024;
    }
}

// ---------------------------------------------------------------------------
// rsig scan (batch-independent), one block; same structure on A1/A2.
// ---------------------------------------------------------------------------
__global__ void __launch_bounds__(512, 1) rsig_kernel(
    const float* __restrict__ xp,
    const float* __restrict__ A1, const float* __restrict__ A2,
    const float* __restrict__ xi1, const float* __restrict__ xi2,
    const float* __restrict__ W2h, const float* __restrict__ b2h,
    const float* __restrict__ W2o, const float* __restrict__ b2o,
    float* __restrict__ rsig_out)
{
    const int tid = threadIdx.x;
    const int q   = tid & 3;
    const int g   = tid >> 2;
    const int q64 = q << 6;
    const int myrow = 2 * g + (q & 1);

    __shared__ __align__(16) uint4 lo_lds[8 * 512];       // 64 KB
    __shared__ __align__(16) float Rs[2][RD];
    __shared__ float dx_lds[NPAST];
    __shared__ float Zlin[RD];
    __shared__ float hh[32];

    RPT16(DECL_W)
    {
        const float sc1 = 1.0f, sc2 = 1.0f;
        const char* pB1 = (const char*)(A1 + (2 * g) * RD) + (q << 8);
        const char* pB2 = (const char*)(A2 + (2 * g) * RD) + (q << 8);
        RPT16(STG)
        RPTP(STO)
    }
    RPT16(KEEPW)

    const float x1m = xi1[myrow];
    const float x2m = xi2[myrow];

    if (tid < NPAST - 1) dx_lds[tid] = xp[tid + 1] - xp[tid];
    ((float*)Rs)[tid] = 0.0f;           // zero both buffers (512 floats)
    __syncthreads();

    float zmine = 0.0f;
    char* RsB = (char*)Rs;
    int rbase = 0;

#pragma unroll 1
    for (int t = 0; t < NPAST - 1; ++t) {
        const float dxt = dx_lds[t];
        const char* RqR = RsB + rbase + (q << 8);
        float acc1_0 = 0.f, acc1_1 = 0.f, acc2_0 = 0.f, acc2_1 = 0.f;
        float accl_0 = 0.f, accl_1 = 0.f;
        RPTP(DOTP)
        float a1_0 = acc1_0, a1_1 = acc1_1;
        float a2_0 = __builtin_fmaf(accl_0, SCLF, acc2_0);
        float a2_1 = __builtin_fmaf(accl_1, SCLF, acc2_1);
        QUADSUM(a1_0) QUADSUM(a1_1) QUADSUM(a2_0) QUADSUM(a2_1)
        float s1 = (q & 1) ? a1_1 : a1_0;
        float s2 = (q & 1) ? a2_1 : a2_0;
        zmine = zmine + ftanh(s1 + x1m) + ftanh(s2 + x2m) * dxt;
        if (q < 2) *(float*)(RsB + (rbase ^ 1024) + myrow * 4) = zmine;
        __syncthreads();
        rbase ^= 1024;
    }

    if (q < 2) Zlin[myrow] = zmine;
    __syncthreads();

    if (tid < 32) {
        float a = b2h[tid];
        const float* wrow = W2h + tid * RD;
        for (int k = 0; k < RD; ++k) a = __builtin_fmaf(wrow[k], Zlin[k], a);
        hh[tid] = ftanh(a);
    }
    __syncthreads();
    if (tid < RD - 30) {
        float a = b2o[tid];
        const float* wrow = W2o + tid * 32;
        for (int k = 0; k < 32; ++k) a = __builtin_fmaf(wrow[k], hh[k], a);
        rsig_out[tid] = a;
    }
}

extern "C" void kernel_launch(void* const* d_in, const int* in_sizes, int n_in,
                              void* d_out, int out_size, void* d_ws, size_t ws_size,
                              hipStream_t stream) {
    const float* x_past  = (const float*)d_in[2];
    const float* V_noise = (const float*)d_in[3];
    const float* inc     = (const float*)d_in[4];
    const float* W1h     = (const float*)d_in[5];
    const float* b1h     = (const float*)d_in[6];
    const float* W1o     = (const float*)d_in[7];
    const float* b1o     = (const float*)d_in[8];
    const float* W2h     = (const float*)d_in[9];
    const float* b2h     = (const float*)d_in[10];
    const float* W2o     = (const float*)d_in[11];
    const float* b2o     = (const float*)d_in[12];
    const float* rho1    = (const float*)d_in[13];
    const float* rho2    = (const float*)d_in[14];
    const float* rho3    = (const float*)d_in[15];
    const float* rho4    = (const float*)d_in[16];
    const float* B1      = (const float*)d_in[17];
    const float* B2      = (const float*)d_in[18];
    const float* lam1    = (const float*)d_in[19];
    const float* lam2    = (const float*)d_in[20];
    const float* A1      = (const float*)d_in[21];
    const float* A2      = (const float*)d_in[22];
    const float* xi1     = (const float*)d_in[23];
    const float* xi2     = (const float*)d_in[24];
    const float* Wr      = (const float*)d_in[25];
    const float* br      = (const float*)d_in[26];

    float* rsig_ws = (float*)d_ws;   // 226 floats

    rsig_kernel<<<1, 512, 0, stream>>>(x_past, A1, A2, xi1, xi2,
                                       W2h, b2h, W2o, b2o, rsig_ws);

    sde_main_kernel<<<256, 512, 0, stream>>>(inc, V_noise, W1h, b1h, W1o, b1o,
                                             rho1, rho2, rho3, rho4,
                                             B1, B2, lam1, lam2, Wr, br,
                                             rsig_ws, (float*)d_out);
}